// Round 4
// baseline (513.804 us; speedup 1.0000x reference)
//
#include <hip/hip_runtime.h>

// Problem constants (from reference)
#define B_    8
#define A_    60000
#define C_    150        // 1 + 10+19+39+69+12
#define G_    20
#define T_    5
#define ROWS  21         // G+1 (row 0 = pad/zero row)
#define NANCH (B_ * A_)          // 480000
#define NTOT  (B_ * A_ * C_)     // 72,000,000
#define TABN  (B_ * ROWS * C_)   // 25200
#define BETA_ (1.0f / 9.0f)

typedef float fx4 __attribute__((ext_vector_type(4)));  // native vec for NT loads

// ---------------------------------------------------------------------------
// Kernel 1: build the 0/1 label table tab[b][g][c] and zero accumulators.
//   c==0       : label for the binary head = (g>0)  (pos <=> idx>0)
//   c in head i: 1 iff any of the T gt labels for (b, g-1, head i) equals class
//   g==0       : all zeros (pad row; also covers labels_bin in {-1,0})
// ---------------------------------------------------------------------------
__global__ void build_table(const int* __restrict__ gt_labels,
                            float* __restrict__ tab,
                            float* __restrict__ accum) {
    int i = blockIdx.x * blockDim.x + threadIdx.x;
    if (i < 4) accum[i] = 0.0f;          // [0]=reg_sum [1]=cls_sum [2]=pos_cnt
    if (i >= TABN) return;
    int c  = i % C_;
    int bg = i / C_;
    int g  = bg % ROWS;
    int b  = bg / ROWS;
    float v = 0.0f;
    if (g > 0) {
        if (c == 0) {
            v = 1.0f;
        } else {
            int cc = c - 1;   // head offsets: 0,10,29,68,137 ; sizes 10,19,39,69,12
            int head, k;
            if      (cc < 10)  { head = 0; k = cc; }
            else if (cc < 29)  { head = 1; k = cc - 10; }
            else if (cc < 68)  { head = 2; k = cc - 29; }
            else if (cc < 137) { head = 3; k = cc - 68; }
            else               { head = 4; k = cc - 137; }
            const int* lp = gt_labels + ((b * G_ + (g - 1)) * 5 + head) * T_;
            v = (lp[0] == k || lp[1] == k || lp[2] == k ||
                 lp[3] == k || lp[4] == k) ? 1.0f : 0.0f;
        }
    }
    tab[i] = v;
}

// Block-wide sum; result valid only in threadIdx.x == 0. Block = 256 (4 waves).
__device__ __forceinline__ float block_reduce_sum(float v, float* sm) {
    #pragma unroll
    for (int off = 32; off > 0; off >>= 1) v += __shfl_down(v, off, 64);
    int lane = threadIdx.x & 63, w = threadIdx.x >> 6;
    if (lane == 0) sm[w] = v;
    __syncthreads();
    float r = 0.0f;
    if (threadIdx.x == 0) r = sm[0] + sm[1] + sm[2] + sm[3];
    __syncthreads();
    return r;
}

__device__ __forceinline__ float sl1(float n) {
    return (n < BETA_) ? (0.5f / BETA_) * n * n : n - 0.5f * BETA_;
}

// ---------------------------------------------------------------------------
// Kernel 2 (fused): phase 1 = smooth-L1 regression + positive count over
// anchors; phase 2 = focal cls sum over all 72M confidence elements.
// Both are independent reductions into accum[] so no sync is needed between.
//
// Focal for label L in {0,1}: with s = L ? x : -x,
//   term = mask * (L ? 0.25 : 0.75) * (1 - sigmoid(s))^2 * log(1 + exp(-s))
// labels_bin distribution: 90% 0 / 5% -1 / 5% pos. l<=0 selects the all-zero
// pad row, so only l>0 anchors ever touch the table -> three paths:
//   l==0 : L=0 closed form, no gather, weight 0.75 hoisted   (90% of anchors)
//   l==-1: mask=0, contribute nothing                         (5%)
//   l> 0 : per-element table gather                           (5%)
// conf is 288 MB streamed once -> non-temporal loads keep L2 for tab/lb.
// ---------------------------------------------------------------------------
__global__ __launch_bounds__(256) void main_kernel(
        const float* __restrict__ conf, const float* __restrict__ pred,
        const float* __restrict__ gt,   const int* __restrict__ lb,
        const float* __restrict__ tab,  float* __restrict__ accum) {
    __shared__ float sm[4];
    const int tid    = blockIdx.x * blockDim.x + threadIdx.x;
    const int stride = gridDim.x * blockDim.x;

    // ---- phase 1: regression (grid covers all anchors in one pass) ----
    float reg = 0.0f, cnt = 0.0f;
    for (int a = tid; a < NANCH; a += stride) {
        int l = lb[a];
        if (l > 0) {
            cnt += 1.0f;
            float4 p = ((const float4*)pred)[a];
            float4 g = ((const float4*)gt)[a];
            reg += sl1(fabsf(p.x - g.x)) + sl1(fabsf(p.y - g.y)) +
                   sl1(fabsf(p.z - g.z)) + sl1(fabsf(p.w - g.w));
        }
    }

    // ---- phase 2: focal cls over float4 chunks ----
    float4 accF = {0.0f, 0.0f, 0.0f, 0.0f};   // fast path, weight hoisted
    float  accG = 0.0f;                        // general path
    const fx4* cp = (const fx4*)conf;
    const int nchunks = NTOT / 4;              // 18,000,000
    for (int ch = tid; ch < nchunks; ch += stride) {
        int e = ch * 4;
        fx4 x = __builtin_nontemporal_load(&cp[ch]);
        int a  = e / C_;                       // magic-mul div by 150
        int c  = e - a * C_;
        int l0 = lb[a];
        bool spans = (c + 3 >= C_);            // chunk crosses into anchor a+1
        int l1 = spans ? lb[a + 1] : l0;

        if ((l0 | l1) == 0) {
            // all labels 0, mask 1; weight 0.75 applied once at the end
            float t0 = __expf(x.x), t1 = __expf(x.y),
                  t2 = __expf(x.z), t3 = __expf(x.w);
            float d0 = 1.0f + t0, d1 = 1.0f + t1,
                  d2 = 1.0f + t2, d3 = 1.0f + t3;
            float s0 = t0 * __builtin_amdgcn_rcpf(d0);   // sigmoid(x)
            float s1 = t1 * __builtin_amdgcn_rcpf(d1);
            float s2 = t2 * __builtin_amdgcn_rcpf(d2);
            float s3 = t3 * __builtin_amdgcn_rcpf(d3);
            accF.x = fmaf(s0 * s0, __logf(d0), accF.x);
            accF.y = fmaf(s1 * s1, __logf(d1), accF.y);
            accF.z = fmaf(s2 * s2, __logf(d2), accF.z);
            accF.w = fmaf(s3 * s3, __logf(d3), accF.w);
        } else if (l0 == -1 && l1 == -1) {
            // ignored anchors: mask 0
        } else {
            // general path (rare): table gather per element
            int b0 = a / A_;
            int row0 = (b0 * ROWS + max(l0, 0)) * C_;
            float m0 = (l0 > -1) ? 1.0f : 0.0f;
            int row1 = row0; float m1 = m0;
            if (spans) {
                int b1 = (a + 1) / A_;
                row1 = (b1 * ROWS + max(l1, 0)) * C_;
                m1 = (l1 > -1) ? 1.0f : 0.0f;
            }
            float xs[4] = {x.x, x.y, x.z, x.w};
            #pragma unroll
            for (int j = 0; j < 4; ++j) {
                int cj = c + j;
                int rb; float mf;
                if (cj < C_) { rb = row0 + cj;      mf = m0; }
                else         { rb = row1 + cj - C_; mf = m1; }
                float L = tab[rb];
                float s = (L + L - 1.0f) * xs[j];
                float t = __expf(-s);
                float denom = 1.0f + t;
                float om  = t * __builtin_amdgcn_rcpf(denom);  // 1 - sigmoid(s)
                float ld  = __logf(denom);                     // log(1 + exp(-s))
                accG += mf * fmaf(L, -0.5f, 0.75f) * (om * om) * ld;
            }
        }
    }
    float cls = fmaf(0.75f, (accF.x + accF.y) + (accF.z + accF.w), accG);

    float rblk = block_reduce_sum(reg, sm);
    float cblk = block_reduce_sum(cnt, sm);
    float sblk = block_reduce_sum(cls, sm);
    if (threadIdx.x == 0) {
        atomicAdd(&accum[0], rblk);
        atomicAdd(&accum[2], cblk);
        atomicAdd(&accum[1], sblk);
    }
}

// ---------------------------------------------------------------------------
// Kernel 3: finalize the two scalar outputs.
// ---------------------------------------------------------------------------
__global__ void finalize(const float* __restrict__ accum, float* __restrict__ out) {
    float np = fmaxf(1.0f, accum[2]);
    out[0] = accum[0] / (np * 4.0f);
    out[1] = accum[1] / (np * 6.0f);
}

extern "C" void kernel_launch(void* const* d_in, const int* in_sizes, int n_in,
                              void* d_out, int out_size, void* d_ws, size_t ws_size,
                              hipStream_t stream) {
    const float* conf = (const float*)d_in[0];
    const float* pred = (const float*)d_in[1];
    const float* gt   = (const float*)d_in[2];
    const int*   gtl  = (const int*)d_in[3];
    // d_in[4] = counts: unused by the reference computation
    const int*   lb   = (const int*)d_in[5];
    float* out   = (float*)d_out;
    float* accum = (float*)d_ws;            // 4 floats
    float* tab   = (float*)d_ws + 64;       // 25200 floats (100 KB)

    build_table<<<(TABN + 255) / 256, 256, 0, stream>>>(gtl, tab, accum);
    main_kernel<<<4096, 256, 0, stream>>>(conf, pred, gt, lb, tab, accum);
    finalize<<<1, 1, 0, stream>>>(accum, out);
}

// Round 5
// 495.183 us; speedup vs baseline: 1.0376x; 1.0376x over previous
//
#include <hip/hip_runtime.h>

// Problem constants (from reference)
#define B_    8
#define A_    60000
#define C_    150        // 1 + 10+19+39+69+12
#define G_    20
#define T_    5
#define ROWS  21         // G+1 (row 0 = pad/zero row)
#define NANCH (B_ * A_)          // 480000
#define NTOT  (B_ * A_ * C_)     // 72,000,000
#define TABN  (B_ * ROWS * C_)   // 25200
#define BETA_ (1.0f / 9.0f)

typedef float fx4 __attribute__((ext_vector_type(4)));

// ---------------------------------------------------------------------------
// Kernel 1: build the 0/1 label table tab[b][g][c] and zero accumulators.
//   c==0       : label for the binary head = (g>0)  (pos <=> idx>0)
//   c in head i: 1 iff any of the T gt labels for (b, g-1, head i) equals class
//   g==0       : all zeros (pad row; also covers labels_bin in {-1,0})
// ---------------------------------------------------------------------------
__global__ void build_table(const int* __restrict__ gt_labels,
                            float* __restrict__ tab,
                            float* __restrict__ accum) {
    int i = blockIdx.x * blockDim.x + threadIdx.x;
    if (i < 4) accum[i] = 0.0f;          // [0]=reg_sum [1]=cls_sum [2]=pos_cnt
    if (i >= TABN) return;
    int c  = i % C_;
    int bg = i / C_;
    int g  = bg % ROWS;
    int b  = bg / ROWS;
    float v = 0.0f;
    if (g > 0) {
        if (c == 0) {
            v = 1.0f;
        } else {
            int cc = c - 1;   // head offsets: 0,10,29,68,137 ; sizes 10,19,39,69,12
            int head, k;
            if      (cc < 10)  { head = 0; k = cc; }
            else if (cc < 29)  { head = 1; k = cc - 10; }
            else if (cc < 68)  { head = 2; k = cc - 29; }
            else if (cc < 137) { head = 3; k = cc - 68; }
            else               { head = 4; k = cc - 137; }
            const int* lp = gt_labels + ((b * G_ + (g - 1)) * 5 + head) * T_;
            v = (lp[0] == k || lp[1] == k || lp[2] == k ||
                 lp[3] == k || lp[4] == k) ? 1.0f : 0.0f;
        }
    }
    tab[i] = v;
}

// Block-wide sum; result valid only in threadIdx.x == 0. Block = 256 (4 waves).
__device__ __forceinline__ float block_reduce_sum(float v, float* sm) {
    #pragma unroll
    for (int off = 32; off > 0; off >>= 1) v += __shfl_down(v, off, 64);
    int lane = threadIdx.x & 63, w = threadIdx.x >> 6;
    if (lane == 0) sm[w] = v;
    __syncthreads();
    float r = 0.0f;
    if (threadIdx.x == 0) r = sm[0] + sm[1] + sm[2] + sm[3];
    __syncthreads();
    return r;
}

__device__ __forceinline__ float sl1(float n) {
    return (n < BETA_) ? (0.5f / BETA_) * n * n : n - 0.5f * BETA_;
}

// Process one float4 conf chunk. x/a/c/l0/l1 precomputed (loads already issued).
__device__ __forceinline__ void proc_chunk(fx4 x, int a, int c, int l0, int l1,
                                           const float* __restrict__ tab,
                                           fx4& accF, float& accG) {
    if ((l0 | l1) == 0) {
        // all labels 0, mask 1; weight 0.75 hoisted to the end of the kernel
        float t0 = __expf(x.x), t1 = __expf(x.y),
              t2 = __expf(x.z), t3 = __expf(x.w);
        float d0 = 1.0f + t0, d1 = 1.0f + t1,
              d2 = 1.0f + t2, d3 = 1.0f + t3;
        float s0 = t0 * __builtin_amdgcn_rcpf(d0);   // sigmoid(x)
        float s1 = t1 * __builtin_amdgcn_rcpf(d1);
        float s2 = t2 * __builtin_amdgcn_rcpf(d2);
        float s3 = t3 * __builtin_amdgcn_rcpf(d3);
        accF.x = fmaf(s0 * s0, __logf(d0), accF.x);
        accF.y = fmaf(s1 * s1, __logf(d1), accF.y);
        accF.z = fmaf(s2 * s2, __logf(d2), accF.z);
        accF.w = fmaf(s3 * s3, __logf(d3), accF.w);
    } else if (l0 == -1 && l1 == -1) {
        // ignored anchors: mask 0 — nothing
    } else {
        // general path (rare): table gather per element
        int b0 = a / A_;
        int row0 = (b0 * ROWS + max(l0, 0)) * C_;
        float m0 = (l0 > -1) ? 1.0f : 0.0f;
        int row1 = row0; float m1 = m0;
        if (c + 3 >= C_) {
            int b1 = (a + 1) / A_;
            row1 = (b1 * ROWS + max(l1, 0)) * C_;
            m1 = (l1 > -1) ? 1.0f : 0.0f;
        }
        float xs[4] = {x.x, x.y, x.z, x.w};
        #pragma unroll
        for (int j = 0; j < 4; ++j) {
            int cj = c + j;
            int rb; float mf;
            if (cj < C_) { rb = row0 + cj;      mf = m0; }
            else         { rb = row1 + cj - C_; mf = m1; }
            float L = tab[rb];
            float s = (L + L - 1.0f) * xs[j];
            float t = __expf(-s);
            float denom = 1.0f + t;
            float om  = t * __builtin_amdgcn_rcpf(denom);  // 1 - sigmoid(s)
            float ld  = __logf(denom);                     // log(1 + exp(-s))
            accG += mf * fmaf(L, -0.5f, 0.75f) * (om * om) * ld;
        }
    }
}

// ---------------------------------------------------------------------------
// Kernel 2 (fused): phase 1 = smooth-L1 regression + positive count;
// phase 2 = focal cls over all 72M confidence elements, 4 chunks in flight
// per thread (MLP=4) with independent accumulators.
// Focal for label L in {0,1}: with s = L ? x : -x,
//   term = mask * (L ? 0.25 : 0.75) * (1 - sigmoid(s))^2 * log(1 + exp(-s))
// labels_bin: 90% 0 / 5% -1 / 5% pos; l<=0 hits the all-zero pad row ->
// fast closed-form path for 95% of waves, gather only for l>0.
// ---------------------------------------------------------------------------
__global__ __launch_bounds__(256) void main_kernel(
        const float* __restrict__ conf, const float* __restrict__ pred,
        const float* __restrict__ gt,   const int* __restrict__ lb,
        const float* __restrict__ tab,  float* __restrict__ accum) {
    __shared__ float sm[4];
    const int tid    = blockIdx.x * blockDim.x + threadIdx.x;
    const int stride = gridDim.x * blockDim.x;

    // ---- phase 1: regression over anchors ----
    float reg = 0.0f, cnt = 0.0f;
    for (int a = tid; a < NANCH; a += stride) {
        int l = lb[a];
        if (l > 0) {
            cnt += 1.0f;
            float4 p = ((const float4*)pred)[a];
            float4 g = ((const float4*)gt)[a];
            reg += sl1(fabsf(p.x - g.x)) + sl1(fabsf(p.y - g.y)) +
                   sl1(fabsf(p.z - g.z)) + sl1(fabsf(p.w - g.w));
        }
    }

    // ---- phase 2: focal cls, 4-way unrolled grid-stride ----
    fx4 accF0 = {0,0,0,0}, accF1 = {0,0,0,0}, accF2 = {0,0,0,0}, accF3 = {0,0,0,0};
    float accG = 0.0f;
    const fx4* cp = (const fx4*)conf;
    const int nchunks = NTOT / 4;              // 18,000,000
    int ch = tid;
    for (; ch + 3 * stride < nchunks; ch += 4 * stride) {
        int c0 = ch, c1 = ch + stride, c2 = ch + 2 * stride, c3 = ch + 3 * stride;
        // issue all 4 vector loads first (independent addresses)
        fx4 x0 = cp[c0], x1 = cp[c1], x2 = cp[c2], x3 = cp[c3];
        int a0 = (c0 * 4) / C_, a1 = (c1 * 4) / C_,
            a2 = (c2 * 4) / C_, a3 = (c3 * 4) / C_;
        int cc0 = c0 * 4 - a0 * C_, cc1 = c1 * 4 - a1 * C_,
            cc2 = c2 * 4 - a2 * C_, cc3 = c3 * 4 - a3 * C_;
        int l00 = lb[a0], l10 = lb[a1], l20 = lb[a2], l30 = lb[a3];
        int l01 = (cc0 + 3 >= C_) ? lb[a0 + 1] : l00;
        int l11 = (cc1 + 3 >= C_) ? lb[a1 + 1] : l10;
        int l21 = (cc2 + 3 >= C_) ? lb[a2 + 1] : l20;
        int l31 = (cc3 + 3 >= C_) ? lb[a3 + 1] : l30;
        proc_chunk(x0, a0, cc0, l00, l01, tab, accF0, accG);
        proc_chunk(x1, a1, cc1, l10, l11, tab, accF1, accG);
        proc_chunk(x2, a2, cc2, l20, l21, tab, accF2, accG);
        proc_chunk(x3, a3, cc3, l30, l31, tab, accF3, accG);
    }
    for (; ch < nchunks; ch += stride) {
        fx4 x = cp[ch];
        int a = (ch * 4) / C_;
        int c = ch * 4 - a * C_;
        int l0 = lb[a];
        int l1 = (c + 3 >= C_) ? lb[a + 1] : l0;
        proc_chunk(x, a, c, l0, l1, tab, accF0, accG);
    }
    fx4 accF = (accF0 + accF1) + (accF2 + accF3);
    float cls = fmaf(0.75f, (accF.x + accF.y) + (accF.z + accF.w), accG);

    float rblk = block_reduce_sum(reg, sm);
    float cblk = block_reduce_sum(cnt, sm);
    float sblk = block_reduce_sum(cls, sm);
    if (threadIdx.x == 0) {
        atomicAdd(&accum[0], rblk);
        atomicAdd(&accum[2], cblk);
        atomicAdd(&accum[1], sblk);
    }
}

// ---------------------------------------------------------------------------
// Kernel 3: finalize the two scalar outputs.
// ---------------------------------------------------------------------------
__global__ void finalize(const float* __restrict__ accum, float* __restrict__ out) {
    float np = fmaxf(1.0f, accum[2]);
    out[0] = accum[0] / (np * 4.0f);
    out[1] = accum[1] / (np * 6.0f);
}

extern "C" void kernel_launch(void* const* d_in, const int* in_sizes, int n_in,
                              void* d_out, int out_size, void* d_ws, size_t ws_size,
                              hipStream_t stream) {
    const float* conf = (const float*)d_in[0];
    const float* pred = (const float*)d_in[1];
    const float* gt   = (const float*)d_in[2];
    const int*   gtl  = (const int*)d_in[3];
    // d_in[4] = counts: unused by the reference computation
    const int*   lb   = (const int*)d_in[5];
    float* out   = (float*)d_out;
    float* accum = (float*)d_ws;            // 4 floats
    float* tab   = (float*)d_ws + 64;       // 25200 floats (100 KB)

    build_table<<<(TABN + 255) / 256, 256, 0, stream>>>(gtl, tab, accum);
    main_kernel<<<4096, 256, 0, stream>>>(conf, pred, gt, lb, tab, accum);
    finalize<<<1, 1, 0, stream>>>(accum, out);
}